// Round 12
// baseline (1200.969 us; speedup 1.0000x reference)
//
#include <hip/hip_runtime.h>
#include <hip/hip_bf16.h>

// Problem constants
#define F_  9
#define B_  8
#define S_  512
#define H_  8
#define DH_ 128
#define D_  128
#define NB_ 50
#define BS_ 4096            // B_*S_ rows per feature
#define PERBUF 4194304UL    // B_*H_*S_*DH_ elements per feature
#define WELEMS 2359296UL    // 2*9*1024*128 elements per projection weight tensor

typedef short bf16x8 __attribute__((ext_vector_type(8)));
typedef float f32x4  __attribute__((ext_vector_type(4)));
typedef unsigned int u32x4 __attribute__((ext_vector_type(4)));

static __device__ __forceinline__ unsigned short f2b(float f) {
    unsigned int u = __float_as_uint(f);
    unsigned int r = (u + 0x7FFFu + ((u >> 16) & 1u)) >> 16;
    return (unsigned short)r;
}
static __device__ __forceinline__ float b2f(unsigned short u) {
    return __uint_as_float(((unsigned int)u) << 16);
}
// pack two f32 -> (lo,hi) bf16 pair in one instr (T12 recipe, m214v22)
static __device__ __forceinline__ unsigned int cvtpk(float lo, float hi) {
    unsigned int r;
    asm("v_cvt_pk_bf16_f32 %0, %1, %2" : "=v"(r) : "v"(lo), "v"(hi));
    return r;
}
// 16B logical load from 8B-aligned LDS rows (two b64 reads)
static __device__ __forceinline__ bf16x8 ld8s(const unsigned short* p) {
    uint2 lo = *(const uint2*)p;
    uint2 hi = *(const uint2*)(p + 4);
    u32x4 u; u[0] = lo.x; u[1] = lo.y; u[2] = hi.x; u[3] = hi.y;
    return __builtin_bit_cast(bf16x8, u);
}
static __device__ __forceinline__ bf16x8 ld8v(const unsigned int* p) {
    uint2 lo = *(const uint2*)p;
    uint2 hi = *(const uint2*)(p + 2);
    u32x4 u; u[0] = lo.x; u[1] = lo.y; u[2] = hi.x; u[3] = hi.y;
    return __builtin_bit_cast(bf16x8, u);
}

// ---------------------------------------------------------------------------
// fp32 -> bf16 bulk convert for the 4 projection weight tensors (fused).
// ---------------------------------------------------------------------------
__global__ __launch_bounds__(256) void cvt4_kernel(
    const float* __restrict__ s0, const float* __restrict__ s1,
    const float* __restrict__ s2, const float* __restrict__ s3,
    unsigned short* __restrict__ d0, unsigned short* __restrict__ d1,
    unsigned short* __restrict__ d2, unsigned short* __restrict__ d3, int n)
{
    const float* s; unsigned short* d;
    switch (blockIdx.y) {
        case 0: s = s0; d = d0; break;
        case 1: s = s1; d = d1; break;
        case 2: s = s2; d = d2; break;
        default: s = s3; d = d3; break;
    }
    int i = (blockIdx.x * 256 + threadIdx.x) * 8;
    if (i + 8 <= n) {
        float4 a = *(const float4*)&s[i];
        float4 b = *(const float4*)&s[i + 4];
        ushort4 o0 = { f2b(a.x), f2b(a.y), f2b(a.z), f2b(a.w) };
        ushort4 o1 = { f2b(b.x), f2b(b.y), f2b(b.z), f2b(b.w) };
        *(ushort4*)&d[i]     = o0;
        *(ushort4*)&d[i + 4] = o1;
    }
}

// ---------------------------------------------------------------------------
// Pos-net v3 (round-8 verified).
// ---------------------------------------------------------------------------
__global__ __launch_bounds__(256) void posnet_kernel(
    const float* __restrict__ Y, const float* __restrict__ Gin,
    const float* __restrict__ W1g, const float* __restrict__ B1,
    const float* __restrict__ W2g, const float* __restrict__ B2,
    const float* __restrict__ W3g, const float* __restrict__ B3,
    float* __restrict__ xA, unsigned short* __restrict__ xAb)
{
    __shared__ float gys[4][8][52];
    __shared__ float hs[4][8][52];

    int f = blockIdx.y;
    int t = threadIdx.x, w = t >> 6, j = t & 63;
    int rowbase = blockIdx.x * 32 + w * 8;

#pragma unroll
    for (int rr = 0; rr < 8; ++rr) {
        int row = rowbase + rr;
        if (j < 50)       gys[w][rr][j]  = Y[(size_t)row*50 + j];
        else if (j == 50) gys[w][rr][50] = Gin[(size_t)row*F_ + f];
    }

    int jj = (j < 50) ? j : 0;

    // ---- layer 1: 51 -> 50, tanh ----
    {
        const float* wp = W1g + f*2550 + jj*51;
        float wreg[51];
#pragma unroll
        for (int kk = 0; kk < 51; ++kk) wreg[kk] = wp[kk];
        float bb = B1[f*50 + jj];
        float acc[8];
#pragma unroll
        for (int rr = 0; rr < 8; ++rr) acc[rr] = bb;
#pragma unroll
        for (int k4 = 0; k4 < 48; k4 += 4) {
#pragma unroll
            for (int rr = 0; rr < 8; ++rr) {
                float4 gv = *(const float4*)&gys[w][rr][k4];
                acc[rr] += wreg[k4]*gv.x + wreg[k4+1]*gv.y + wreg[k4+2]*gv.z + wreg[k4+3]*gv.w;
            }
        }
#pragma unroll
        for (int kk = 48; kk < 51; ++kk)
#pragma unroll
            for (int rr = 0; rr < 8; ++rr) acc[rr] += wreg[kk]*gys[w][rr][kk];
        if (j < 50) {
#pragma unroll
            for (int rr = 0; rr < 8; ++rr) hs[w][rr][j] = tanhf(acc[rr]);
        }
    }

    // ---- layer 2: 50 -> 50, tanh ----
    {
        const float* wp = W2g + f*2500 + jj*50;
        float wreg[50];
#pragma unroll
        for (int kk = 0; kk < 50; ++kk) wreg[kk] = wp[kk];
        float bb = B2[f*50 + jj];
        float acc[8];
#pragma unroll
        for (int rr = 0; rr < 8; ++rr) acc[rr] = bb;
#pragma unroll
        for (int k4 = 0; k4 < 48; k4 += 4) {
#pragma unroll
            for (int rr = 0; rr < 8; ++rr) {
                float4 gv = *(const float4*)&hs[w][rr][k4];
                acc[rr] += wreg[k4]*gv.x + wreg[k4+1]*gv.y + wreg[k4+2]*gv.z + wreg[k4+3]*gv.w;
            }
        }
#pragma unroll
        for (int kk = 48; kk < 50; ++kk)
#pragma unroll
            for (int rr = 0; rr < 8; ++rr) acc[rr] += wreg[kk]*hs[w][rr][kk];
        if (j < 50) {
#pragma unroll
            for (int rr = 0; rr < 8; ++rr) gys[w][rr][j] = tanhf(acc[rr]);
        }
    }

    // ---- layer 3: 50 -> 128, sigmoid; two passes of 64 neurons ----
#pragma unroll 1
    for (int ppass = 0; ppass < 2; ++ppass) {
        const float* wp = W3g + f*6400 + (ppass*64 + j)*50;
        float wreg[50];
#pragma unroll
        for (int kk = 0; kk < 50; ++kk) wreg[kk] = wp[kk];
        float bb = B3[f*128 + ppass*64 + j];
        float acc[8];
#pragma unroll
        for (int rr = 0; rr < 8; ++rr) acc[rr] = bb;
#pragma unroll
        for (int k4 = 0; k4 < 48; k4 += 4) {
#pragma unroll
            for (int rr = 0; rr < 8; ++rr) {
                float4 gv = *(const float4*)&gys[w][rr][k4];
                acc[rr] += wreg[k4]*gv.x + wreg[k4+1]*gv.y + wreg[k4+2]*gv.z + wreg[k4+3]*gv.w;
            }
        }
#pragma unroll
        for (int kk = 48; kk < 50; ++kk)
#pragma unroll
            for (int rr = 0; rr < 8; ++rr) acc[rr] += wreg[kk]*gys[w][rr][kk];
#pragma unroll
        for (int rr = 0; rr < 8; ++rr) {
            float x = 1.f / (1.f + expf(-acc[rr]));
            size_t roff = ((size_t)f*BS_ + rowbase + rr)*128 + ppass*64 + j;
            xA[roff]  = x;
            xAb[roff] = f2b(x);
        }
    }
}

// ---------------------------------------------------------------------------
// QKV projection via MFMA (round-3 verified). q PRE-SCALED by 1/sqrt(128).
// ---------------------------------------------------------------------------
__global__ __launch_bounds__(256) void qkv_mfma_kernel(
    const unsigned short* __restrict__ xb,
    const unsigned short* __restrict__ Wqb, const unsigned short* __restrict__ Wkb,
    const unsigned short* __restrict__ Wvb,
    const float* __restrict__ bq, const float* __restrict__ bk, const float* __restrict__ bv,
    unsigned short* __restrict__ qo, unsigned short* __restrict__ ko,
    unsigned int* __restrict__ vto, int l, int f0)
{
    int z = blockIdx.z;
    int fl = z / 3, which = z - fl*3;
    int f = f0 + fl;
    const unsigned short* W; const float* bias;
    if (which == 0)      { W = Wqb; bias = bq; }
    else if (which == 1) { W = Wkb; bias = bk; }
    else                 { W = Wvb; bias = bv; }
    W    += (size_t)(l*F_ + f) * 1024 * 128;
    bias += (size_t)(l*F_ + f) * 1024;

    int m0 = blockIdx.x * 128;
    int n0 = blockIdx.y * 128;
    int t = threadIdx.x, w = t >> 6, ln = t & 63, g = ln >> 4, c = ln & 15;
    int wr = w >> 1, wc = w & 1;

    const unsigned short* Ab = xb + ((size_t)f*BS_ + m0 + wr*64)*128;
    const unsigned short* Bb = W + (size_t)(n0 + wc*64)*128;

    f32x4 acc[4][4];
#pragma unroll
    for (int mi = 0; mi < 4; ++mi)
#pragma unroll
        for (int ni = 0; ni < 4; ++ni) acc[mi][ni] = (f32x4){0.f,0.f,0.f,0.f};

#pragma unroll
    for (int kt = 0; kt < 4; ++kt) {
        bf16x8 af[4], bfr[4];
#pragma unroll
        for (int mi = 0; mi < 4; ++mi)
            af[mi] = *(const bf16x8*)&Ab[(size_t)(mi*16 + c)*128 + kt*32 + g*8];
#pragma unroll
        for (int ni = 0; ni < 4; ++ni)
            bfr[ni] = *(const bf16x8*)&Bb[(size_t)(ni*16 + c)*128 + kt*32 + g*8];
#pragma unroll
        for (int mi = 0; mi < 4; ++mi)
#pragma unroll
            for (int ni = 0; ni < 4; ++ni)
                acc[mi][ni] = __builtin_amdgcn_mfma_f32_16x16x32_bf16(af[mi], bfr[ni], acc[mi][ni], 0, 0, 0);
    }

    int h = n0 >> 7;
    float bs_[4];
#pragma unroll
    for (int ni = 0; ni < 4; ++ni) bs_[ni] = bias[n0 + wc*64 + ni*16 + c];

    if (which < 2) {
        float qscale = (which == 0) ? 0.08838834764831845f : 1.0f;
        unsigned short* out = (which == 0 ? qo : ko) + (size_t)fl * PERBUF;
#pragma unroll
        for (int mi = 0; mi < 4; ++mi) {
#pragma unroll
            for (int r = 0; r < 4; ++r) {
                int m = m0 + wr*64 + mi*16 + 4*g + r;
                int b = m >> 9, s = m & 511;
                unsigned short* orow = out + (((size_t)(b*H_ + h))*S_ + s)*128;
#pragma unroll
                for (int ni = 0; ni < 4; ++ni)
                    orow[wc*64 + ni*16 + c] = f2b((acc[mi][ni][r] + bs_[ni]) * qscale);
            }
        }
    } else {
        unsigned int* vtf = vto + (size_t)fl * (PERBUF/2);
#pragma unroll
        for (int mi = 0; mi < 4; ++mi) {
            int mbase = m0 + wr*64 + mi*16 + 4*g;
            int b = mbase >> 9, sh = (mbase & 511) >> 1;
            unsigned int* vtp = vtf + ((size_t)(b*H_ + h))*32768;
#pragma unroll
            for (int ni = 0; ni < 4; ++ni) {
                int d = wc*64 + ni*16 + c;
                float bb_ = bs_[ni];
                unsigned int p01 = (unsigned int)f2b(acc[mi][ni][0] + bb_)
                                 | ((unsigned int)f2b(acc[mi][ni][1] + bb_) << 16);
                unsigned int p23 = (unsigned int)f2b(acc[mi][ni][2] + bb_)
                                 | ((unsigned int)f2b(acc[mi][ni][3] + bb_) << 16);
                vtp[(size_t)d*256 + sh]     = p01;
                vtp[(size_t)d*256 + sh + 1] = p23;
            }
        }
    }
}

// ---------------------------------------------------------------------------
// MFMA flash attention (round-8 verified structure). Changes this round:
//  (a) conflict-free LDS pitches: Ks 136->132 shorts (66 dw: bank start
//      2(c+2g) mod 32 -> 16 groups x 4 lanes = floor), Vs 20->18 dw
//      (2(9c+2g) mod 32 -> 16 groups). Rows 8B-aligned -> all 16B LDS
//      accesses split into b64 pairs (ld8s/ld8v + uint2 stores).
//  (b) single barrier per kt (writes at iter k target the buffer last read
//      at k-1; the k-1 barrier orders them).
// Math/indices byte-identical to round 8.
// ---------------------------------------------------------------------------
__global__ __launch_bounds__(256) void attn_mfma_kernel(
    const unsigned short* __restrict__ q, const unsigned short* __restrict__ k,
    const unsigned int* __restrict__ vt, unsigned short* __restrict__ wv)
{
    int t = threadIdx.x;
    int w = t >> 6, ln = t & 63, g = ln >> 4, c = ln & 15;
    int bid = blockIdx.x;
    int group = bid >> 5, within = bid & 31;
    int i = within >> 3, hl = within & 7;
    int hIdx = group*8 + hl;                 // 0 .. 64*fc-1
    int fl = hIdx >> 6, by = hIdx & 63;
    int q0 = i*128 + w*32;

    const unsigned short* qh = q + ((size_t)(fl*64 + by))*S_*128;
    const unsigned short* kh = k + ((size_t)(fl*64 + by))*S_*128;
    const unsigned int*  vth = vt + ((size_t)(fl*64 + by))*32768;
    int b = by >> 3, h = by & 7;
    unsigned short* wvh = wv + ((size_t)(fl*B_ + b))*S_*1024 + h*128;

    __shared__ alignas(16) unsigned short Ks[2][32][132];  // 16896 B
    __shared__ alignas(16) unsigned int   Vs[2][128][18];  // 18432 B

    // staging index split (256 threads)
    int krow = t >> 4, kseg = t & 15;   // K rows krow, krow+16 ; 16B segs
    int vrow = t >> 2, vseg = t & 3;    // V rows vrow, vrow+64 ; 16B segs

    bf16x8 qf[2][4];
#pragma unroll
    for (int gq = 0; gq < 2; ++gq)
#pragma unroll
        for (int d0 = 0; d0 < 4; ++d0)
            qf[gq][d0] = *(const bf16x8*)&qh[(size_t)(q0 + gq*16 + c)*128 + d0*32 + g*8];

    f32x4 acc[2][8];
#pragma unroll
    for (int gq = 0; gq < 2; ++gq)
#pragma unroll
        for (int i2 = 0; i2 < 8; ++i2) acc[gq][i2] = (f32x4){0.f, 0.f, 0.f, 0.f};
    float mrow[2] = {-1e30f, -1e30f};
    float lrow[2] = {0.f, 0.f};

    int srcA = ((g & 1) << 5) + c;   // source lane for low half of A-frag
    int srcB = srcA + 16;
    bool glow = (g < 2);

    uint4 kr0, kr1, vr0, vr1;
    // prologue: tile 0 -> buf 0
    {
        kr0 = *(const uint4*)&kh[(size_t)krow*128 + kseg*8];
        kr1 = *(const uint4*)&kh[(size_t)(krow + 16)*128 + kseg*8];
        vr0 = *(const uint4*)&vth[(size_t)vrow*256 + vseg*4];
        vr1 = *(const uint4*)&vth[(size_t)(vrow + 64)*256 + vseg*4];
        *(uint2*)&Ks[0][krow][kseg*8]          = make_uint2(kr0.x, kr0.y);
        *(uint2*)&Ks[0][krow][kseg*8 + 4]      = make_uint2(kr0.z, kr0.w);
        *(uint2*)&Ks[0][krow + 16][kseg*8]     = make_uint2(kr1.x, kr1.y);
        *(uint2*)&Ks[0][krow + 16][kseg*8 + 4] = make_uint2(kr1.z, kr1.w);
        *(uint2*)&Vs[0][vrow][vseg*4]          = make_uint2(vr0.x, vr0.y);
        *(uint2*)&Vs[0][vrow][vseg*4 + 2]      = make_uint2(vr0.z, vr0.w);
        *(uint2*)&Vs[0][vrow + 64][vseg*4]     = make_uint2(vr1.x, vr1.y);
        *(uint2*)&Vs[0][vrow + 64][vseg*4 + 2] = make_uint2(vr1.z, vr1.w);
    }
    __syncthreads();

    int cur = 0;
    for (int kt = 0; kt < 16; ++kt) {
        if (kt < 15) {
            const unsigned short* ks = kh + (size_t)(kt + 1)*32*128;
            const unsigned int*  vsp = vth + (kt + 1)*16;
            kr0 = *(const uint4*)&ks[(size_t)krow*128 + kseg*8];
            kr1 = *(const uint4*)&ks[(size_t)(krow + 16)*128 + kseg*8];
            vr0 = *(const uint4*)&vsp[(size_t)vrow*256 + vseg*4];
            vr1 = *(const uint4*)&vsp[(size_t)(vrow + 64)*256 + vseg*4];
        }

        // QK^T (swapped): s[gq][tile] = S^T[key][qrow]
        f32x4 s[2][2];
        s[0][0] = (f32x4){0.f,0.f,0.f,0.f}; s[0][1] = (f32x4){0.f,0.f,0.f,0.f};
        s[1][0] = (f32x4){0.f,0.f,0.f,0.f}; s[1][1] = (f32x4){0.f,0.f,0.f,0.f};
        __builtin_amdgcn_s_setprio(1);
#pragma unroll
        for (int d0 = 0; d0 < 4; ++d0) {
            bf16x8 k0 = ld8s(&Ks[cur][c][g*8 + d0*32]);
            bf16x8 k1 = ld8s(&Ks[cur][16 + c][g*8 + d0*32]);
#pragma unroll
            for (int gq = 0; gq < 2; ++gq) {
                s[gq][0] = __builtin_amdgcn_mfma_f32_16x16x32_bf16(k0, qf[gq][d0], s[gq][0], 0, 0, 0);
                s[gq][1] = __builtin_amdgcn_mfma_f32_16x16x32_bf16(k1, qf[gq][d0], s[gq][1], 0, 0, 0);
            }
        }
        __builtin_amdgcn_s_setprio(0);

        // softmax: lane owns qrow c for each gq; keys in regs (4g+r, 16+4g+r)
        float corr[2];
        bf16x8 pa[2];
        bool need = false;
#pragma unroll
        for (int gq = 0; gq < 2; ++gq) {
            float t0 = fmaxf(fmaxf(fmaxf(s[gq][0][0], s[gq][0][1]), fmaxf(s[gq][0][2], s[gq][0][3])),
                             fmaxf(fmaxf(s[gq][1][0], s[gq][1][1]), fmaxf(s[gq][1][2], s[gq][1][3])));
            t0 = fmaxf(t0, __shfl_xor(t0, 16));
            t0 = fmaxf(t0, __shfl_xor(t0, 32));
            float mo = mrow[gq];
            float mn = (t0 > mo + 8.f) ? t0 : mo;
            float co = __expf(mo - mn);
            corr[gq] = co;
            mrow[gq] = mn;
            float p00 = __expf(s[gq][0][0] - mn), p01 = __expf(s[gq][0][1] - mn);
            float p02 = __expf(s[gq][0][2] - mn), p03 = __expf(s[gq][0][3] - mn);
            float p10 = __expf(s[gq][1][0] - mn), p11 = __expf(s[gq][1][1] - mn);
            float p12 = __expf(s[gq][1][2] - mn), p13 = __expf(s[gq][1][3] - mn);
            float ps = ((p00 + p01) + (p02 + p03)) + ((p10 + p11) + (p12 + p13));
            ps += __shfl_xor(ps, 16);
            ps += __shfl_xor(ps, 32);
            lrow[gq] = lrow[gq]*co + ps;
            need = need || (co != 1.0f);

            // pack P to bf16 pairs and redistribute to A-frag layout
            unsigned int pk0 = cvtpk(p00, p01), pk1 = cvtpk(p02, p03);
            unsigned int pk2 = cvtpk(p10, p11), pk3 = cvtpk(p12, p13);
            unsigned int a0 = __shfl(pk0, srcA), a1 = __shfl(pk1, srcA);
            unsigned int b0 = __shfl(pk0, srcB), b1 = __shfl(pk1, srcB);
            unsigned int c0 = __shfl(pk2, srcA), c1 = __shfl(pk3, srcA);
            unsigned int d0_ = __shfl(pk2, srcB), d1_ = __shfl(pk3, srcB);
            u32x4 pu;
            pu[0] = glow ? a0 : c0;
            pu[1] = glow ? a1 : c1;
            pu[2] = glow ? b0 : d0_;
            pu[3] = glow ? b1 : d1_;
            pa[gq] = __builtin_bit_cast(bf16x8, pu);
        }

        if (__any(need)) {
#pragma unroll
            for (int gq = 0; gq < 2; ++gq) {
                float cr0 = __shfl(corr[gq], 4*g + 0);
                float cr1 = __shfl(corr[gq], 4*g + 1);
                float cr2 = __shfl(corr[gq], 4*g + 2);
                float cr3 = __shfl(corr[gq], 4*g + 3);
#pragma unroll
                for (int i2 = 0; i2 < 8; ++i2) {
                    f32x4 a = acc[gq][i2];
                    a[0] *= cr0; a[1] *= cr1; a[2] *= cr2; a[3] *= cr3;
                    acc[gq][i2] = a;
                }
            }
        }

        // PV
        __builtin_amdgcn_s_setprio(1);
#pragma unroll
        for (int i2 = 0; i2 < 8; ++i2) {
            bf16x8 vf = ld8v(&Vs[cur][i2*16 + c][g*4]);
            acc[0][i2] = __builtin_amdgcn_mfma_f32_16x16x32_bf16(pa[0], vf, acc[0][i2], 0, 0, 0);
            acc[1][i2] = __builtin_amdgcn_mfma_f32_16x16x32_bf16(pa[1], vf, acc[1][i2], 0, 0, 0);
        }
        __builtin_amdgcn_s_setprio(0);

        if (kt < 15) {
            int nxt = cur ^ 1;
            // writes target the buffer last read at kt-1; the barrier at the
            // end of kt-1 ordered those reads before these writes.
            *(uint2*)&Ks[nxt][krow][kseg*8]          = make_uint2(kr0.x, kr0.y);
            *(uint2*)&Ks[nxt][krow][kseg*8 + 4]      = make_uint2(kr0.z, kr0.w);
            *(uint2*)&Ks[nxt][krow + 16][kseg*8]     = make_uint2(kr1.x, kr1.y);
            *(uint2*)&Ks[nxt][krow + 16][kseg*8 + 4] = make_uint2(kr1.z, kr1.w);
            *(uint2*)&Vs[nxt][vrow][vseg*4]          = make_uint2(vr0.x, vr0.y);
            *(uint2*)&Vs[nxt][vrow][vseg*4 + 2]      = make_uint2(vr0.z, vr0.w);
            *(uint2*)&Vs[nxt][vrow + 64][vseg*4]     = make_uint2(vr1.x, vr1.y);
            *(uint2*)&Vs[nxt][vrow + 64][vseg*4 + 2] = make_uint2(vr1.z, vr1.w);
            __syncthreads();
            cur = nxt;
        }
    }

    // epilogue: 1/l per q-row (held at lane c), redistribute to (g,r)
#pragma unroll
    for (int gq = 0; gq < 2; ++gq) {
        float invq = 1.0f / lrow[gq];
        float iv0 = __shfl(invq, 4*g + 0);
        float iv1 = __shfl(invq, 4*g + 1);
        float iv2 = __shfl(invq, 4*g + 2);
        float iv3 = __shfl(invq, 4*g + 3);
#pragma unroll
        for (int i2 = 0; i2 < 8; ++i2) {
            unsigned short* wp = &wvh[(size_t)(q0 + gq*16 + 4*g)*1024 + i2*16 + c];
            wp[0]    = f2b(acc[gq][i2][0]*iv0);
            wp[1024] = f2b(acc[gq][i2][1]*iv1);
            wp[2048] = f2b(acc[gq][i2][2]*iv2);
            wp[3072] = f2b(acc[gq][i2][3]*iv3);
        }
    }
}

// ---------------------------------------------------------------------------
// FUSED out-projection + residual + LayerNorm, 64-ROW tiles (round-8
// verified outproj body; grid 64 x fc = 320 blocks restores parallelism
// vs round-11's 128-row fusion). In-place on xA (reads precede barrier).
// ---------------------------------------------------------------------------
__global__ __launch_bounds__(256) void outproj_ln_kernel(
    const unsigned short* __restrict__ wv, const unsigned short* __restrict__ Wob,
    const float* __restrict__ bo, float* __restrict__ xA,
    unsigned short* __restrict__ xAb,
    const float* __restrict__ lnGb, const float* __restrict__ lnBb,
    int l, int f0)
{
    __shared__ float Xs[64][132];    // 33792 B

    int fl = blockIdx.z, f = f0 + fl;
    int m0 = blockIdx.x * 64;
    int t = threadIdx.x, w = t >> 6, ln = t & 63, g = ln >> 4, c = ln & 15;

    const unsigned short* Ab = wv + ((size_t)fl*BS_ + m0 + w*16)*1024;
    const unsigned short* Bb = Wob + (size_t)(l*F_ + f)*128*1024;
    const float* bob = bo + (size_t)(l*F_ + f)*128;

    f32x4 acc[8];
#pragma unroll
    for (int ni = 0; ni < 8; ++ni) acc[ni] = (f32x4){0.f,0.f,0.f,0.f};

#pragma unroll 4
    for (int kt = 0; kt < 32; ++kt) {
        bf16x8 af = *(const bf16x8*)&Ab[(size_t)c*1024 + kt*32 + g*8];
#pragma unroll
        for (int ni = 0; ni < 8; ++ni) {
            bf16x8 bfr = *(const bf16x8*)&Bb[(size_t)(ni*16 + c)*1024 + kt*32 + g*8];
            acc[ni] = __builtin_amdgcn_mfma_f32_16x16x32_bf16(af, bfr, acc[ni], 0, 0, 0);
        }
    }

    // stage result + bias + residual into LDS (all xA reads happen here)
#pragma unroll
    for (int r = 0; r < 4; ++r) {
        int lm = w*16 + 4*g + r;
        const float* xr = xA + ((size_t)f*BS_ + m0 + lm)*128;
#pragma unroll
        for (int ni = 0; ni < 8; ++ni) {
            int n = ni*16 + c;
            Xs[lm][n] = acc[ni][r] + bob[n] + xr[n];
        }
    }
    __syncthreads();

    // LN per row (ln_kernel math): wave w handles rows w, w+4, ...
    const float* gp = lnGb + (size_t)fl*128;
    const float* bp = lnBb + (size_t)fl*128;
    float g0 = gp[ln], g1 = gp[64 + ln];
    float b0 = bp[ln], b1 = bp[64 + ln];
#pragma unroll 1
    for (int rr = w; rr < 64; rr += 4) {
        float a = Xs[rr][ln], cv = Xs[rr][64 + ln];
        float s = a + cv;
#pragma unroll
        for (int off = 1; off < 64; off <<= 1) s += __shfl_xor(s, off);
        float mean = s * (1.0f/128.0f);
        float da = a - mean, dc = cv - mean;
        float vs = da*da + dc*dc;
#pragma unroll
        for (int off = 1; off < 64; off <<= 1) vs += __shfl_xor(vs, off);
        float inv = rsqrtf(vs * (1.0f/128.0f) + 1e-5f);
        float o0 = da*inv*g0 + b0;
        float o1 = dc*inv*g1 + b1;
        size_t row = (size_t)f*BS_ + m0 + rr;
        xA[row*128 + ln]       = o0;
        xA[row*128 + 64 + ln]  = o1;
        xAb[row*128 + ln]      = f2b(o0);
        xAb[row*128 + 64 + ln] = f2b(o1);
    }
}

// ---------------------------------------------------------------------------
// LayerNorm over last dim (128). One wave per row. Emits fp32 + bf16.
// (Used only for the final fnG/fnB LN before pooling.)
// ---------------------------------------------------------------------------
__global__ __launch_bounds__(256) void ln_kernel(
    const float* __restrict__ xin, float* __restrict__ xout,
    unsigned short* __restrict__ xoutb,
    const float* __restrict__ g, const float* __restrict__ bb, int f0, int gstride)
{
    int t = threadIdx.x, lane = t & 63, w = t >> 6;
    int rowl = blockIdx.x * 4 + w;
    int fl = rowl >> 12;
    size_t row = (size_t)f0*BS_ + rowl;
    const float* xi = xin + row*128;
    float a = xi[lane], c = xi[64 + lane];
    float s = a + c;
#pragma unroll
    for (int off = 1; off < 64; off <<= 1) s += __shfl_xor(s, off);
    float mean = s * (1.0f/128.0f);
    float da = a - mean, dc = c - mean;
    float vs = da*da + dc*dc;
#pragma unroll
    for (int off = 1; off < 64; off <<= 1) vs += __shfl_xor(vs, off);
    float inv = rsqrtf(vs * (1.0f/128.0f) + 1e-5f);
    const float* gp = g + (size_t)fl*gstride;
    const float* bp = bb + (size_t)fl*gstride;
    float o0 = da*inv*gp[lane]      + bp[lane];
    float o1 = dc*inv*gp[64 + lane] + bp[64 + lane];
    float* xo = xout + row*128;
    xo[lane]      = o0;
    xo[64 + lane] = o1;
    xoutb[row*128 + lane]      = f2b(o0);
    xoutb[row*128 + 64 + lane] = f2b(o1);
}

// ---------------------------------------------------------------------------
// Softmax-pool over S (unchanged).
// ---------------------------------------------------------------------------
__global__ __launch_bounds__(256) void pool_kernel(
    const float* __restrict__ xB, const float* __restrict__ poolW,
    float* __restrict__ U, int f0)
{
    int f = f0 + blockIdx.x, b = blockIdx.y;
    const float* xb = xB + ((size_t)f*BS_ + (size_t)b*S_)*128;
    const float* pw = poolW + f*128;
    __shared__ float sc[512];
    __shared__ float red[8];
    __shared__ float MS[2];
    __shared__ float pool2[256];
    int t = threadIdx.x, lane = t & 63, w = t >> 6;

    float p0 = pw[lane], p1 = pw[64 + lane];
    for (int s = w; s < 512; s += 4) {
        float a = xb[(size_t)s*128 + lane]*p0 + xb[(size_t)s*128 + 64 + lane]*p1;
#pragma unroll
        for (int off = 1; off < 64; off <<= 1) a += __shfl_xor(a, off);
        if (lane == 0) sc[s] = a;
    }
    __syncthreads();

    float m = -1e30f;
    for (int s = t; s < 512; s += 256) m = fmaxf(m, sc[s]);
#pragma unroll
    for (int off = 1; off < 64; off <<= 1) m = fmaxf(m, __shfl_xor(m, off));
    if (lane == 0) red[w] = m;
    __syncthreads();
    if (t == 0) MS[0] = fmaxf(fmaxf(red[0], red[1]), fmaxf(red[2], red[3]));
    __syncthreads();
    float M = MS[0];

    float ssum = 0.f;
    for (int s = t; s < 512; s += 256) { float e = expf(sc[s] - M); sc[s] = e; ssum += e; }
#pragma unroll
    for (int off = 1; off < 64; off <<= 1) ssum += __shfl_xor(ssum, off);
    if (lane == 0) red[4 + w] = ssum;
    __syncthreads();
    if (t == 0) MS[1] = red[4] + red[5] + red[6] + red[7];
    __syncthreads();
    float inv = 1.0f / MS[1];

    int d = t & 127, hh = t >> 7;
    float a = 0.f;
    for (int s = hh*256; s < hh*256 + 256; ++s) a += sc[s]*xb[(size_t)s*128 + d];
    pool2[t] = a;
    __syncthreads();
    if (t < 128) U[((size_t)b*128 + d)*F_ + f] = (pool2[t] + pool2[t + 128]) * inv;
}

// ---------------------------------------------------------------------------
// Unified attention per (f,b) (unchanged).
// ---------------------------------------------------------------------------
__global__ __launch_bounds__(256) void unified_kernel(
    const float* __restrict__ U,
    const float* __restrict__ uQW, const float* __restrict__ uQB,
    const float* __restrict__ uKW, const float* __restrict__ uKB,
    const float* __restrict__ uVW, const float* __restrict__ uVB,
    float* __restrict__ outp)
{
    int f = blockIdx.x, b = blockIdx.y;
    __shared__ float Ub[128*9];
    __shared__ float Wj[128*9];
    __shared__ float zj[128];
    __shared__ float vm[128];
    __shared__ float Mm[81];
    __shared__ float wvm[9], bvec[9];
    __shared__ float cc_[2];
    int t = threadIdx.x;
    for (int i = t; i < 1152; i += 256) Ub[i] = U[(size_t)b*1152 + i];
    const float* qw = uQW + (size_t)f*1152;
    const float* kw = uKW + (size_t)f*1152;
    const float* vw = uVW + (size_t)f*1152;
    const float* qb = uQB + (size_t)f*128;
    const float* kb = uKB + (size_t)f*128;
    const float* vb = uVB + (size_t)f*128;

    if (t < 81) {
        int t1 = t/9, s1 = t%9; float a = 0.f;
        for (int kk = 0; kk < 128; ++kk) a += qw[kk*9 + t1]*kw[kk*9 + s1];
        Mm[t] = a;
    } else if (t < 90) {
        int s1 = t - 81; float a = 0.f;
        for (int kk = 0; kk < 128; ++kk) a += kw[kk*9 + s1]*qb[kk];
        bvec[s1] = a;
    } else if (t < 99) {
        int t1 = t - 90; float a = 0.f;
        for (int kk = 0; kk < 128; ++kk) a += vw[kk*9 + t1];
        wvm[t1] = a * (1.0f/128.0f);
    } else if (t == 99) {
        float a = 0.f, c2 = 0.f;
        for (int kk = 0; kk < 128; ++kk) { a += qb[kk]*kb[kk]; c2 += vb[kk]; }
        cc_[0] = a; cc_[1] = c2 * (1.0f/128.0f);
    }
    __syncthreads();

    if (t < 128) {
        int j = t;
        for (int t1 = 0; t1 < 9; ++t1) {
            float a = 0.f;
            for (int s1 = 0; s1 < 9; ++s1) a += Mm[t1*9 + s1]*Ub[j*9 + s1];
            Wj[j*9 + t1] = a;
        }
        float z = cc_[0], v2 = cc_[1];
        for (int s1 = 0; s1 < 9; ++s1) { z += bvec[s1]*Ub[j*9 + s1]; v2 += wvm[s1]*Ub[j*9 + s1]; }
        zj[j] = z; vm[j] = v2;
    }
    __syncthreads();

    int i = t >> 1, half = t & 1;
    float ui[9];
#pragma unroll
    for (int s1 = 0; s1 < 9; ++s1) ui[s1] = Ub[i*9 + s1];

    float mx = -1e30f;
    for (int jj = 0; jj < 64; ++jj) {
        int j = half*64 + jj;
        float a = zj[j];
#pragma unroll
        for (int s1 = 0; s1 < 9; ++s1) a += ui[s1]*Wj[j*9 + s1];
        mx = fmaxf(mx, a * (1.0f/3.0f));
    }
    mx = fmaxf(mx, __shfl_xor(mx, 1));
    float sum = 0.f, o = 0.f;
    for (int jj = 0; jj < 64; ++jj) {
        int j = half*64 + jj;
        float a = zj[j];
#pragma unroll
        for (int s1 = 0; s1 < 9; ++s1) a += ui[s1]*Wj[j*9 + s1];
        float p = expf(a * (1.0f/3.0f) - mx);
        sum += p; o += p*vm[j];
    }
    sum += __shfl_xor(sum, 1);
    o   += __shfl_xor(o, 1);
    if (half == 0) {
        float base;
        if (f > 0) base = ui[f];
        else { base = 0.f; for (int s1 = 0; s1 < 9; ++s1) base += ui[s1]; base *= (1.0f/9.0f); }
        outp[((size_t)b*128 + i)*10 + f] = o/sum + base;
    }
}

// ---------------------------------------------------------------------------
// Merge attention (features 3..8), writes output column 9 (unchanged).
// ---------------------------------------------------------------------------
__global__ __launch_bounds__(256) void merge_kernel(
    const float* __restrict__ U,
    const float* __restrict__ mQW, const float* __restrict__ mQB,
    const float* __restrict__ mKW, const float* __restrict__ mKB,
    const float* __restrict__ mVW, const float* __restrict__ mVB,
    float* __restrict__ outp)
{
    int b = blockIdx.x;
    __shared__ float Us[128*6];
    __shared__ float Wj[128*6];
    __shared__ float zj[128];
    __shared__ float vm[128];
    __shared__ float Mm[36];
    __shared__ float wvm[6], bvec[6];
    __shared__ float cc_[2];
    int t = threadIdx.x;
    for (int i = t; i < 768; i += 256) {
        int j = i/6, tt = i - j*6;
        Us[i] = U[(size_t)b*1152 + j*9 + 3 + tt];
    }
    if (t < 36) {
        int t1 = t/6, s1 = t%6; float a = 0.f;
        for (int kk = 0; kk < 128; ++kk) a += mQW[kk*6 + t1]*mKW[kk*6 + s1];
        Mm[t] = a;
    } else if (t < 42) {
        int s1 = t - 36; float a = 0.f;
        for (int kk = 0; kk < 128; ++kk) a += mKW[kk*6 + s1]*mQB[kk];
        bvec[s1] = a;
    } else if (t < 48) {
        int t1 = t - 42; float a = 0.f;
        for (int kk = 0; kk < 128; ++kk) a += mVW[kk*6 + t1];
        wvm[t1] = a * (1.0f/128.0f);
    } else if (t == 48) {
        float a = 0.f, c2 = 0.f;
        for (int kk = 0; kk < 128; ++kk) { a += mQB[kk]*mKB[kk]; c2 += mVB[kk]; }
        cc_[0] = a; cc_[1] = c2 * (1.0f/128.0f);
    }
    __syncthreads();

    if (t < 128) {
        int j = t;
        for (int t1 = 0; t1 < 6; ++t1) {
            float a = 0.f;
            for (int s1 = 0; s1 < 6; ++s1) a += Mm[t1*6 + s1]*Us[j*6 + s1];
            Wj[j*6 + t1] = a;
        }
        float z = cc_[0], v2 = cc_[1];
        for (int s1 = 0; s1 < 6; ++s1) { z += bvec[s1]*Us[j*6 + s1]; v2 += wvm[s1]*Us[j*6 + s1]; }
        zj[j] = z; vm[j] = v2;
    }
    __syncthreads();

    int i = t >> 1, half = t & 1;
    float ui[6];
#pragma unroll
    for (int s1 = 0; s1 < 6; ++s1) ui[s1] = Us[i*6 + s1];

    float mx = -1e30f;
    for (int jj = 0; jj < 64; ++jj) {
        int j = half*64 + jj;
        float a = zj[j];
#pragma unroll
        for (int s1 = 0; s1 < 6; ++s1) a += ui[s1]*Wj[j*6 + s1];
        mx = fmaxf(mx, a * (1.0f/3.0f));
    }
    mx = fmaxf(mx, __shfl_xor(mx, 1));
    float sum = 0.f, o = 0.f;
    for (int jj = 0; jj < 64; ++jj) {
        int j = half*64 + jj;
        float a = zj[j];
#pragma unroll
        for (int s1 = 0; s1 < 6; ++s1) a += ui[s1]*Wj[j*6 + s1];
        float p = expf(a * (1.0f/3.0f) - mx);
        sum += p; o += p*vm[j];
    }
    sum += __shfl_xor(sum, 1);
    o   += __shfl_xor(o, 1);
    if (half == 0) {
        float base = 0.f;
        for (int s1 = 0; s1 < 6; ++s1) base += ui[s1];
        base *= (1.0f/6.0f);
        outp[((size_t)b*128 + i)*10 + 9] = o/sum + base;
    }
}

// ---------------------------------------------------------------------------
extern "C" void kernel_launch(void* const* d_in, const int* in_sizes, int n_in,
                              void* d_out, int out_size, void* d_ws, size_t ws_size,
                              hipStream_t stream)
{
    const float* Y     = (const float*)d_in[0];
    const float* Gin   = (const float*)d_in[1];
    const float* posW1 = (const float*)d_in[2];
    const float* posB1 = (const float*)d_in[3];
    const float* posW2 = (const float*)d_in[4];
    const float* posB2 = (const float*)d_in[5];
    const float* posW3 = (const float*)d_in[6];
    const float* posB3 = (const float*)d_in[7];
    const float* Wq    = (const float*)d_in[8];
    const float* bq    = (const float*)d_in[9];
    const float* Wk    = (const float*)d_in[10];
    const float* bk    = (const float*)d_in[11];
    const float* Wv    = (const float*)d_in[12];
    const float* bv    = (const float*)d_in[13];
    const float* Wo    = (const float*)d_in[14];
    const float* bo    = (const float*)d_in[15];
    const float* lnG   = (const float*)d_in[16];
    const float* lnB   = (const float*)d_in[17];
    const float* fnG   = (const float*)d_in[18];
    const float* fnB   = (const float*)d_in[19];
    const float* poolW = (const float*)d_in[20];
    const float* uQW   = (const float*)d_in[21];
    const float* uQB   = (const float*)d_in[22];
    const float* uKW   = (const float*)d_in[23];
    const float* uKB   = (const float*)d_in[24];
    const float* uVW   = (const float*)d_in[25];
    const float* uVB   = (const float*)d_in[26];
    const float* mQW   = (const float*)d_in[27];
    const float* mQB   = (const float*)d_in[28];
    const float* mKW   = (const float*)d_in[29];
    const float* mKB   = (const float*)d_in[30];
    const float* mVW   = (const float*)d_in[31];
    const float* mVB   = (const float*)d_in[32];

    const size_t xelems = (size_t)F_ * BS_ * 128;     // 4,718,592
    char* p = (char*)d_ws;
    float* xA   = (float*)p;               p += xelems*4;
    float* xB   = (float*)p;               p += xelems*4;
    float* Ubuf = (float*)p;               p += 16384*4;
    unsigned short* xAb = (unsigned short*)p; p += xelems*2;
    unsigned short* Wqb = (unsigned short*)p; p += WELEMS*2;
    unsigned short* Wkb = (unsigned short*)p; p += WELEMS*2;
    unsigned short* Wvb = (unsigned short*)p; p += WELEMS*2;
    unsigned short* Wob = (unsigned short*)p; p += WELEMS*2;
    size_t fixed_bytes = (size_t)(p - (char*)d_ws);

    size_t avail = (ws_size > fixed_bytes) ? (ws_size - fixed_bytes) : 0;
    size_t per_f = 8UL * PERBUF;            // q(2B)+k(2B)+wv(2B)+Vt(2B eff) per elem
    int FC = (int)(avail / per_f);
    if (FC < 1) FC = 1;
    if (FC > F_) FC = F_;

    unsigned short* qb  = (unsigned short*)p;
    unsigned short* kb  = qb + (size_t)FC*PERBUF;
    unsigned short* wvb = kb + (size_t)FC*PERBUF;
    unsigned int*   vtb = (unsigned int*)(wvb + (size_t)FC*PERBUF);

    // Weight conversion to bf16 (once per launch, ~19 MB, single kernel)
    {
        int n = (int)WELEMS, gx = (n/8 + 255)/256;
        cvt4_kernel<<<dim3(gx, 4), 256, 0, stream>>>(
            Wq, Wk, Wv, Wo, Wqb, Wkb, Wvb, Wob, n);
    }

    posnet_kernel<<<dim3(128, F_), 256, 0, stream>>>(
        Y, Gin, posW1, posB1, posW2, posB2, posW3, posB3, xA, xAb);

    for (int l = 0; l < 2; ++l) {
        for (int f0 = 0; f0 < F_; f0 += FC) {
            int fc = (F_ - f0) < FC ? (F_ - f0) : FC;
            qkv_mfma_kernel<<<dim3(32, 8, 3*fc), 256, 0, stream>>>(
                xAb, Wqb, Wkb, Wvb, bq, bk, bv, qb, kb, vtb, l, f0);
            attn_mfma_kernel<<<dim3(256*fc), 256, 0, stream>>>(qb, kb, vtb, wvb);
            outproj_ln_kernel<<<dim3(64, 1, fc), 256, 0, stream>>>(
                wvb, Wob, bo, xA, xAb,
                lnG + (size_t)(l*F_ + f0)*128, lnB + (size_t)(l*F_ + f0)*128, l, f0);
        }
    }

    for (int f0 = 0; f0 < F_; f0 += FC) {
        int fc = (F_ - f0) < FC ? (F_ - f0) : FC;
        ln_kernel<<<dim3(fc*1024), 256, 0, stream>>>(xA, xB, xAb, fnG, fnB, f0, 0);
        pool_kernel<<<dim3(fc, 8), 256, 0, stream>>>(xB, poolW, Ubuf, f0);
    }

    unified_kernel<<<dim3(F_, B_), 256, 0, stream>>>(
        Ubuf, uQW, uQB, uKW, uKB, uVW, uVB, (float*)d_out);
    merge_kernel<<<dim3(B_), 256, 0, stream>>>(
        Ubuf, mQW, mQB, mKW, mKB, mVW, mVB, (float*)d_out);
}

// Round 13
// 1057.581 us; speedup vs baseline: 1.1356x; 1.1356x over previous
//
#include <hip/hip_runtime.h>
#include <hip/hip_bf16.h>

// Problem constants
#define F_  9
#define B_  8
#define S_  512
#define H_  8
#define DH_ 128
#define D_  128
#define NB_ 50
#define BS_ 4096            // B_*S_ rows per feature
#define PERBUF 4194304UL    // B_*H_*S_*DH_ elements per feature
#define WELEMS 2359296UL    // 2*9*1024*128 elements per projection weight tensor

typedef short bf16x8 __attribute__((ext_vector_type(8)));
typedef float f32x4  __attribute__((ext_vector_type(4)));
typedef unsigned int u32x4 __attribute__((ext_vector_type(4)));

static __device__ __forceinline__ unsigned short f2b(float f) {
    unsigned int u = __float_as_uint(f);
    unsigned int r = (u + 0x7FFFu + ((u >> 16) & 1u)) >> 16;
    return (unsigned short)r;
}
static __device__ __forceinline__ float b2f(unsigned short u) {
    return __uint_as_float(((unsigned int)u) << 16);
}
// pack two f32 -> (lo,hi) bf16 pair in one instr (T12 recipe, m214v22)
static __device__ __forceinline__ unsigned int cvtpk(float lo, float hi) {
    unsigned int r;
    asm("v_cvt_pk_bf16_f32 %0, %1, %2" : "=v"(r) : "v"(lo), "v"(hi));
    return r;
}

// ---------------------------------------------------------------------------
// fp32 -> bf16 bulk convert for the 4 projection weight tensors (fused).
// ---------------------------------------------------------------------------
__global__ __launch_bounds__(256) void cvt4_kernel(
    const float* __restrict__ s0, const float* __restrict__ s1,
    const float* __restrict__ s2, const float* __restrict__ s3,
    unsigned short* __restrict__ d0, unsigned short* __restrict__ d1,
    unsigned short* __restrict__ d2, unsigned short* __restrict__ d3, int n)
{
    const float* s; unsigned short* d;
    switch (blockIdx.y) {
        case 0: s = s0; d = d0; break;
        case 1: s = s1; d = d1; break;
        case 2: s = s2; d = d2; break;
        default: s = s3; d = d3; break;
    }
    int i = (blockIdx.x * 256 + threadIdx.x) * 8;
    if (i + 8 <= n) {
        float4 a = *(const float4*)&s[i];
        float4 b = *(const float4*)&s[i + 4];
        ushort4 o0 = { f2b(a.x), f2b(a.y), f2b(a.z), f2b(a.w) };
        ushort4 o1 = { f2b(b.x), f2b(b.y), f2b(b.z), f2b(b.w) };
        *(ushort4*)&d[i]     = o0;
        *(ushort4*)&d[i + 4] = o1;
    }
}

// ---------------------------------------------------------------------------
// Pos-net v3 (round-8 verified): weights-in-registers, LDS broadcast,
// 8-row acc chains, layer-scoped wreg, layer3 in two passes (no spill).
// ---------------------------------------------------------------------------
__global__ __launch_bounds__(256) void posnet_kernel(
    const float* __restrict__ Y, const float* __restrict__ Gin,
    const float* __restrict__ W1g, const float* __restrict__ B1,
    const float* __restrict__ W2g, const float* __restrict__ B2,
    const float* __restrict__ W3g, const float* __restrict__ B3,
    float* __restrict__ xA, unsigned short* __restrict__ xAb)
{
    __shared__ float gys[4][8][52];
    __shared__ float hs[4][8][52];

    int f = blockIdx.y;
    int t = threadIdx.x, w = t >> 6, j = t & 63;
    int rowbase = blockIdx.x * 32 + w * 8;

#pragma unroll
    for (int rr = 0; rr < 8; ++rr) {
        int row = rowbase + rr;
        if (j < 50)       gys[w][rr][j]  = Y[(size_t)row*50 + j];
        else if (j == 50) gys[w][rr][50] = Gin[(size_t)row*F_ + f];
    }

    int jj = (j < 50) ? j : 0;

    // ---- layer 1: 51 -> 50, tanh ----
    {
        const float* wp = W1g + f*2550 + jj*51;
        float wreg[51];
#pragma unroll
        for (int kk = 0; kk < 51; ++kk) wreg[kk] = wp[kk];
        float bb = B1[f*50 + jj];
        float acc[8];
#pragma unroll
        for (int rr = 0; rr < 8; ++rr) acc[rr] = bb;
#pragma unroll
        for (int k4 = 0; k4 < 48; k4 += 4) {
#pragma unroll
            for (int rr = 0; rr < 8; ++rr) {
                float4 gv = *(const float4*)&gys[w][rr][k4];
                acc[rr] += wreg[k4]*gv.x + wreg[k4+1]*gv.y + wreg[k4+2]*gv.z + wreg[k4+3]*gv.w;
            }
        }
#pragma unroll
        for (int kk = 48; kk < 51; ++kk)
#pragma unroll
            for (int rr = 0; rr < 8; ++rr) acc[rr] += wreg[kk]*gys[w][rr][kk];
        if (j < 50) {
#pragma unroll
            for (int rr = 0; rr < 8; ++rr) hs[w][rr][j] = tanhf(acc[rr]);
        }
    }

    // ---- layer 2: 50 -> 50, tanh ----
    {
        const float* wp = W2g + f*2500 + jj*50;
        float wreg[50];
#pragma unroll
        for (int kk = 0; kk < 50; ++kk) wreg[kk] = wp[kk];
        float bb = B2[f*50 + jj];
        float acc[8];
#pragma unroll
        for (int rr = 0; rr < 8; ++rr) acc[rr] = bb;
#pragma unroll
        for (int k4 = 0; k4 < 48; k4 += 4) {
#pragma unroll
            for (int rr = 0; rr < 8; ++rr) {
                float4 gv = *(const float4*)&hs[w][rr][k4];
                acc[rr] += wreg[k4]*gv.x + wreg[k4+1]*gv.y + wreg[k4+2]*gv.z + wreg[k4+3]*gv.w;
            }
        }
#pragma unroll
        for (int kk = 48; kk < 50; ++kk)
#pragma unroll
            for (int rr = 0; rr < 8; ++rr) acc[rr] += wreg[kk]*hs[w][rr][kk];
        if (j < 50) {
#pragma unroll
            for (int rr = 0; rr < 8; ++rr) gys[w][rr][j] = tanhf(acc[rr]);
        }
    }

    // ---- layer 3: 50 -> 128, sigmoid; two passes of 64 neurons ----
#pragma unroll 1
    for (int ppass = 0; ppass < 2; ++ppass) {
        const float* wp = W3g + f*6400 + (ppass*64 + j)*50;
        float wreg[50];
#pragma unroll
        for (int kk = 0; kk < 50; ++kk) wreg[kk] = wp[kk];
        float bb = B3[f*128 + ppass*64 + j];
        float acc[8];
#pragma unroll
        for (int rr = 0; rr < 8; ++rr) acc[rr] = bb;
#pragma unroll
        for (int k4 = 0; k4 < 48; k4 += 4) {
#pragma unroll
            for (int rr = 0; rr < 8; ++rr) {
                float4 gv = *(const float4*)&gys[w][rr][k4];
                acc[rr] += wreg[k4]*gv.x + wreg[k4+1]*gv.y + wreg[k4+2]*gv.z + wreg[k4+3]*gv.w;
            }
        }
#pragma unroll
        for (int kk = 48; kk < 50; ++kk)
#pragma unroll
            for (int rr = 0; rr < 8; ++rr) acc[rr] += wreg[kk]*gys[w][rr][kk];
#pragma unroll
        for (int rr = 0; rr < 8; ++rr) {
            float x = 1.f / (1.f + expf(-acc[rr]));
            size_t roff = ((size_t)f*BS_ + rowbase + rr)*128 + ppass*64 + j;
            xA[roff]  = x;
            xAb[roff] = f2b(x);
        }
    }
}

// ---------------------------------------------------------------------------
// QKV projection via MFMA (round-3 verified). q PRE-SCALED by 1/sqrt(128).
// which==0/1 -> q/k row-major bf16 [bh][s][dh]; which==2 -> Vt packed u32.
// ---------------------------------------------------------------------------
__global__ __launch_bounds__(256) void qkv_mfma_kernel(
    const unsigned short* __restrict__ xb,
    const unsigned short* __restrict__ Wqb, const unsigned short* __restrict__ Wkb,
    const unsigned short* __restrict__ Wvb,
    const float* __restrict__ bq, const float* __restrict__ bk, const float* __restrict__ bv,
    unsigned short* __restrict__ qo, unsigned short* __restrict__ ko,
    unsigned int* __restrict__ vto, int l, int f0)
{
    int z = blockIdx.z;
    int fl = z / 3, which = z - fl*3;
    int f = f0 + fl;
    const unsigned short* W; const float* bias;
    if (which == 0)      { W = Wqb; bias = bq; }
    else if (which == 1) { W = Wkb; bias = bk; }
    else                 { W = Wvb; bias = bv; }
    W    += (size_t)(l*F_ + f) * 1024 * 128;
    bias += (size_t)(l*F_ + f) * 1024;

    int m0 = blockIdx.x * 128;
    int n0 = blockIdx.y * 128;
    int t = threadIdx.x, w = t >> 6, ln = t & 63, g = ln >> 4, c = ln & 15;
    int wr = w >> 1, wc = w & 1;

    const unsigned short* Ab = xb + ((size_t)f*BS_ + m0 + wr*64)*128;
    const unsigned short* Bb = W + (size_t)(n0 + wc*64)*128;

    f32x4 acc[4][4];
#pragma unroll
    for (int mi = 0; mi < 4; ++mi)
#pragma unroll
        for (int ni = 0; ni < 4; ++ni) acc[mi][ni] = (f32x4){0.f,0.f,0.f,0.f};

#pragma unroll
    for (int kt = 0; kt < 4; ++kt) {
        bf16x8 af[4], bfr[4];
#pragma unroll
        for (int mi = 0; mi < 4; ++mi)
            af[mi] = *(const bf16x8*)&Ab[(size_t)(mi*16 + c)*128 + kt*32 + g*8];
#pragma unroll
        for (int ni = 0; ni < 4; ++ni)
            bfr[ni] = *(const bf16x8*)&Bb[(size_t)(ni*16 + c)*128 + kt*32 + g*8];
#pragma unroll
        for (int mi = 0; mi < 4; ++mi)
#pragma unroll
            for (int ni = 0; ni < 4; ++ni)
                acc[mi][ni] = __builtin_amdgcn_mfma_f32_16x16x32_bf16(af[mi], bfr[ni], acc[mi][ni], 0, 0, 0);
    }

    int h = n0 >> 7;
    float bs_[4];
#pragma unroll
    for (int ni = 0; ni < 4; ++ni) bs_[ni] = bias[n0 + wc*64 + ni*16 + c];

    if (which < 2) {
        float qscale = (which == 0) ? 0.08838834764831845f : 1.0f;
        unsigned short* out = (which == 0 ? qo : ko) + (size_t)fl * PERBUF;
#pragma unroll
        for (int mi = 0; mi < 4; ++mi) {
#pragma unroll
            for (int r = 0; r < 4; ++r) {
                int m = m0 + wr*64 + mi*16 + 4*g + r;
                int b = m >> 9, s = m & 511;
                unsigned short* orow = out + (((size_t)(b*H_ + h))*S_ + s)*128;
#pragma unroll
                for (int ni = 0; ni < 4; ++ni)
                    orow[wc*64 + ni*16 + c] = f2b((acc[mi][ni][r] + bs_[ni]) * qscale);
            }
        }
    } else {
        unsigned int* vtf = vto + (size_t)fl * (PERBUF/2);
#pragma unroll
        for (int mi = 0; mi < 4; ++mi) {
            int mbase = m0 + wr*64 + mi*16 + 4*g;
            int b = mbase >> 9, sh = (mbase & 511) >> 1;
            unsigned int* vtp = vtf + ((size_t)(b*H_ + h))*32768;
#pragma unroll
            for (int ni = 0; ni < 4; ++ni) {
                int d = wc*64 + ni*16 + c;
                float bb_ = bs_[ni];
                unsigned int p01 = (unsigned int)f2b(acc[mi][ni][0] + bb_)
                                 | ((unsigned int)f2b(acc[mi][ni][1] + bb_) << 16);
                unsigned int p23 = (unsigned int)f2b(acc[mi][ni][2] + bb_)
                                 | ((unsigned int)f2b(acc[mi][ni][3] + bb_) << 16);
                vtp[(size_t)d*256 + sh]     = p01;
                vtp[(size_t)d*256 + sh + 1] = p23;
            }
        }
    }
}

// ---------------------------------------------------------------------------
// MFMA flash attention (round-8 VERIFIED b128 layout; only delta vs R8 is
// the single-barrier-per-kt schedule, hardware-validated correct in R12:
// writes at iter kt target the buffer last read at kt-1; the barrier at the
// end of kt-1 orders those reads before these writes).
// Swapped QK^T + LDS double-buffered pipeline, 32 q-rows/wave (gq=2),
// grid 256*fc, decode group=bid>>5. gq=4 widening failed twice (R9/R10) —
// do not retry without an isolation campaign.
// ---------------------------------------------------------------------------
__global__ __launch_bounds__(256) void attn_mfma_kernel(
    const unsigned short* __restrict__ q, const unsigned short* __restrict__ k,
    const unsigned int* __restrict__ vt, unsigned short* __restrict__ wv)
{
    int t = threadIdx.x;
    int w = t >> 6, ln = t & 63, g = ln >> 4, c = ln & 15;
    int bid = blockIdx.x;
    int group = bid >> 5, within = bid & 31;
    int i = within >> 3, hl = within & 7;
    int hIdx = group*8 + hl;                 // 0 .. 64*fc-1
    int fl = hIdx >> 6, by = hIdx & 63;
    int q0 = i*128 + w*32;

    const unsigned short* qh = q + ((size_t)(fl*64 + by))*S_*128;
    const unsigned short* kh = k + ((size_t)(fl*64 + by))*S_*128;
    const unsigned int*  vth = vt + ((size_t)(fl*64 + by))*32768;
    int b = by >> 3, h = by & 7;
    unsigned short* wvh = wv + ((size_t)(fl*B_ + b))*S_*1024 + h*128;

    __shared__ alignas(16) unsigned short Ks[2][32][136];  // 17408 B
    __shared__ alignas(16) unsigned int   Vs[2][128][20];  // 20480 B

    // staging index split (256 threads)
    int krow = t >> 4, kseg = t & 15;   // K rows krow, krow+16 ; 16B segs
    int vrow = t >> 2, vseg = t & 3;    // V rows vrow, vrow+64 ; 16B segs

    bf16x8 qf[2][4];
#pragma unroll
    for (int gq = 0; gq < 2; ++gq)
#pragma unroll
        for (int d0 = 0; d0 < 4; ++d0)
            qf[gq][d0] = *(const bf16x8*)&qh[(size_t)(q0 + gq*16 + c)*128 + d0*32 + g*8];

    f32x4 acc[2][8];
#pragma unroll
    for (int gq = 0; gq < 2; ++gq)
#pragma unroll
        for (int i2 = 0; i2 < 8; ++i2) acc[gq][i2] = (f32x4){0.f, 0.f, 0.f, 0.f};
    float mrow[2] = {-1e30f, -1e30f};
    float lrow[2] = {0.f, 0.f};

    int srcA = ((g & 1) << 5) + c;   // source lane for low half of A-frag
    int srcB = srcA + 16;
    bool glow = (g < 2);

    uint4 kr0, kr1, vr0, vr1;
    // prologue: tile 0 -> buf 0
    {
        kr0 = *(const uint4*)&kh[(size_t)krow*128 + kseg*8];
        kr1 = *(const uint4*)&kh[(size_t)(krow + 16)*128 + kseg*8];
        vr0 = *(const uint4*)&vth[(size_t)vrow*256 + vseg*4];
        vr1 = *(const uint4*)&vth[(size_t)(vrow + 64)*256 + vseg*4];
        *(uint4*)&Ks[0][krow][kseg*8]      = kr0;
        *(uint4*)&Ks[0][krow + 16][kseg*8] = kr1;
        *(uint4*)&Vs[0][vrow][vseg*4]      = vr0;
        *(uint4*)&Vs[0][vrow + 64][vseg*4] = vr1;
    }
    __syncthreads();

    int cur = 0;
    for (int kt = 0; kt < 16; ++kt) {
        if (kt < 15) {
            const unsigned short* ks = kh + (size_t)(kt + 1)*32*128;
            const unsigned int*  vsp = vth + (kt + 1)*16;
            kr0 = *(const uint4*)&ks[(size_t)krow*128 + kseg*8];
            kr1 = *(const uint4*)&ks[(size_t)(krow + 16)*128 + kseg*8];
            vr0 = *(const uint4*)&vsp[(size_t)vrow*256 + vseg*4];
            vr1 = *(const uint4*)&vsp[(size_t)(vrow + 64)*256 + vseg*4];
        }

        // QK^T (swapped): s[gq][tile] = S^T[key][qrow]
        f32x4 s[2][2];
        s[0][0] = (f32x4){0.f,0.f,0.f,0.f}; s[0][1] = (f32x4){0.f,0.f,0.f,0.f};
        s[1][0] = (f32x4){0.f,0.f,0.f,0.f}; s[1][1] = (f32x4){0.f,0.f,0.f,0.f};
        __builtin_amdgcn_s_setprio(1);
#pragma unroll
        for (int d0 = 0; d0 < 4; ++d0) {
            bf16x8 k0 = *(const bf16x8*)&Ks[cur][c][g*8 + d0*32];
            bf16x8 k1 = *(const bf16x8*)&Ks[cur][16 + c][g*8 + d0*32];
#pragma unroll
            for (int gq = 0; gq < 2; ++gq) {
                s[gq][0] = __builtin_amdgcn_mfma_f32_16x16x32_bf16(k0, qf[gq][d0], s[gq][0], 0, 0, 0);
                s[gq][1] = __builtin_amdgcn_mfma_f32_16x16x32_bf16(k1, qf[gq][d0], s[gq][1], 0, 0, 0);
            }
        }
        __builtin_amdgcn_s_setprio(0);

        // softmax: lane owns qrow c for each gq; keys in regs (4g+r, 16+4g+r)
        float corr[2];
        bf16x8 pa[2];
        bool need = false;
#pragma unroll
        for (int gq = 0; gq < 2; ++gq) {
            float t0 = fmaxf(fmaxf(fmaxf(s[gq][0][0], s[gq][0][1]), fmaxf(s[gq][0][2], s[gq][0][3])),
                             fmaxf(fmaxf(s[gq][1][0], s[gq][1][1]), fmaxf(s[gq][1][2], s[gq][1][3])));
            t0 = fmaxf(t0, __shfl_xor(t0, 16));
            t0 = fmaxf(t0, __shfl_xor(t0, 32));
            float mo = mrow[gq];
            float mn = (t0 > mo + 8.f) ? t0 : mo;
            float co = __expf(mo - mn);
            corr[gq] = co;
            mrow[gq] = mn;
            float p00 = __expf(s[gq][0][0] - mn), p01 = __expf(s[gq][0][1] - mn);
            float p02 = __expf(s[gq][0][2] - mn), p03 = __expf(s[gq][0][3] - mn);
            float p10 = __expf(s[gq][1][0] - mn), p11 = __expf(s[gq][1][1] - mn);
            float p12 = __expf(s[gq][1][2] - mn), p13 = __expf(s[gq][1][3] - mn);
            float ps = ((p00 + p01) + (p02 + p03)) + ((p10 + p11) + (p12 + p13));
            ps += __shfl_xor(ps, 16);
            ps += __shfl_xor(ps, 32);
            lrow[gq] = lrow[gq]*co + ps;
            need = need || (co != 1.0f);

            // pack P to bf16 pairs and redistribute to A-frag layout
            unsigned int pk0 = cvtpk(p00, p01), pk1 = cvtpk(p02, p03);
            unsigned int pk2 = cvtpk(p10, p11), pk3 = cvtpk(p12, p13);
            unsigned int a0 = __shfl(pk0, srcA), a1 = __shfl(pk1, srcA);
            unsigned int b0 = __shfl(pk0, srcB), b1 = __shfl(pk1, srcB);
            unsigned int c0 = __shfl(pk2, srcA), c1 = __shfl(pk3, srcA);
            unsigned int d0_ = __shfl(pk2, srcB), d1_ = __shfl(pk3, srcB);
            u32x4 pu;
            pu[0] = glow ? a0 : c0;
            pu[1] = glow ? a1 : c1;
            pu[2] = glow ? b0 : d0_;
            pu[3] = glow ? b1 : d1_;
            pa[gq] = __builtin_bit_cast(bf16x8, pu);
        }

        if (__any(need)) {
#pragma unroll
            for (int gq = 0; gq < 2; ++gq) {
                float cr0 = __shfl(corr[gq], 4*g + 0);
                float cr1 = __shfl(corr[gq], 4*g + 1);
                float cr2 = __shfl(corr[gq], 4*g + 2);
                float cr3 = __shfl(corr[gq], 4*g + 3);
#pragma unroll
                for (int i2 = 0; i2 < 8; ++i2) {
                    f32x4 a = acc[gq][i2];
                    a[0] *= cr0; a[1] *= cr1; a[2] *= cr2; a[3] *= cr3;
                    acc[gq][i2] = a;
                }
            }
        }

        // PV
        __builtin_amdgcn_s_setprio(1);
#pragma unroll
        for (int i2 = 0; i2 < 8; ++i2) {
            bf16x8 vf = *(const bf16x8*)&Vs[cur][i2*16 + c][g*4];
            acc[0][i2] = __builtin_amdgcn_mfma_f32_16x16x32_bf16(pa[0], vf, acc[0][i2], 0, 0, 0);
            acc[1][i2] = __builtin_amdgcn_mfma_f32_16x16x32_bf16(pa[1], vf, acc[1][i2], 0, 0, 0);
        }
        __builtin_amdgcn_s_setprio(0);

        if (kt < 15) {
            int nxt = cur ^ 1;
            // single barrier: buf nxt's last reads happened at kt-1, already
            // ordered before these writes by the barrier at the end of kt-1.
            *(uint4*)&Ks[nxt][krow][kseg*8]      = kr0;
            *(uint4*)&Ks[nxt][krow + 16][kseg*8] = kr1;
            *(uint4*)&Vs[nxt][vrow][vseg*4]      = vr0;
            *(uint4*)&Vs[nxt][vrow + 64][vseg*4] = vr1;
            __syncthreads();
            cur = nxt;
        }
    }

    // epilogue: 1/l per q-row (held at lane c), redistribute to (g,r)
#pragma unroll
    for (int gq = 0; gq < 2; ++gq) {
        float invq = 1.0f / lrow[gq];
        float iv0 = __shfl(invq, 4*g + 0);
        float iv1 = __shfl(invq, 4*g + 1);
        float iv2 = __shfl(invq, 4*g + 2);
        float iv3 = __shfl(invq, 4*g + 3);
#pragma unroll
        for (int i2 = 0; i2 < 8; ++i2) {
            unsigned short* wp = &wvh[(size_t)(q0 + gq*16 + 4*g)*1024 + i2*16 + c];
            wp[0]    = f2b(acc[gq][i2][0]*iv0);
            wp[1024] = f2b(acc[gq][i2][1]*iv1);
            wp[2048] = f2b(acc[gq][i2][2]*iv2);
            wp[3072] = f2b(acc[gq][i2][3]*iv3);
        }
    }
}

// ---------------------------------------------------------------------------
// Out-projection via MFMA + residual (round-8 verified): 128x128 tile,
// 4 waves (2x2), 4x4 frags/wave, K=1024. fp32 out to xB.
// ---------------------------------------------------------------------------
__global__ __launch_bounds__(256) void outproj_mfma_kernel(
    const unsigned short* __restrict__ wv, const unsigned short* __restrict__ Wob,
    const float* __restrict__ bo, const float* __restrict__ xin,
    float* __restrict__ xout, int l, int f0)
{
    int fl = blockIdx.z, f = f0 + fl;
    int m0 = blockIdx.x * 128;
    int t = threadIdx.x, w = t >> 6, ln = t & 63, g = ln >> 4, c = ln & 15;
    int wr = w >> 1, wc = w & 1;

    const unsigned short* Ab = wv + ((size_t)fl*BS_ + m0 + wr*64)*1024;
    const unsigned short* Bb = Wob + (size_t)(l*F_ + f)*128*1024 + (size_t)(wc*64)*1024;
    const float* bob = bo + (size_t)(l*F_ + f)*128;

    f32x4 acc[4][4];
#pragma unroll
    for (int mi = 0; mi < 4; ++mi)
#pragma unroll
        for (int ni = 0; ni < 4; ++ni) acc[mi][ni] = (f32x4){0.f,0.f,0.f,0.f};

#pragma unroll 4
    for (int kt = 0; kt < 32; ++kt) {
        bf16x8 af[4], bfr[4];
#pragma unroll
        for (int mi = 0; mi < 4; ++mi)
            af[mi] = *(const bf16x8*)&Ab[(size_t)(mi*16 + c)*1024 + kt*32 + g*8];
#pragma unroll
        for (int ni = 0; ni < 4; ++ni)
            bfr[ni] = *(const bf16x8*)&Bb[(size_t)(ni*16 + c)*1024 + kt*32 + g*8];
#pragma unroll
        for (int mi = 0; mi < 4; ++mi)
#pragma unroll
            for (int ni = 0; ni < 4; ++ni)
                acc[mi][ni] = __builtin_amdgcn_mfma_f32_16x16x32_bf16(af[mi], bfr[ni], acc[mi][ni], 0, 0, 0);
    }

    float bs_[4];
#pragma unroll
    for (int ni = 0; ni < 4; ++ni) bs_[ni] = bob[wc*64 + ni*16 + c];

#pragma unroll
    for (int mi = 0; mi < 4; ++mi) {
#pragma unroll
        for (int r = 0; r < 4; ++r) {
            int m = m0 + wr*64 + mi*16 + 4*g + r;
            const float* xr = xin + ((size_t)f*BS_ + m)*128;
            float* xo = xout + ((size_t)f*BS_ + m)*128;
#pragma unroll
            for (int ni = 0; ni < 4; ++ni) {
                int n = wc*64 + ni*16 + c;
                xo[n] = acc[mi][ni][r] + bs_[ni] + xr[n];
            }
        }
    }
}

// ---------------------------------------------------------------------------
// LayerNorm over last dim (128). One wave per row. Emits fp32 + bf16.
// ---------------------------------------------------------------------------
__global__ __launch_bounds__(256) void ln_kernel(
    const float* __restrict__ xin, float* __restrict__ xout,
    unsigned short* __restrict__ xoutb,
    const float* __restrict__ g, const float* __restrict__ bb, int f0, int gstride)
{
    int t = threadIdx.x, lane = t & 63, w = t >> 6;
    int rowl = blockIdx.x * 4 + w;
    int fl = rowl >> 12;
    size_t row = (size_t)f0*BS_ + rowl;
    const float* xi = xin + row*128;
    float a = xi[lane], c = xi[64 + lane];
    float s = a + c;
#pragma unroll
    for (int off = 1; off < 64; off <<= 1) s += __shfl_xor(s, off);
    float mean = s * (1.0f/128.0f);
    float da = a - mean, dc = c - mean;
    float vs = da*da + dc*dc;
#pragma unroll
    for (int off = 1; off < 64; off <<= 1) vs += __shfl_xor(vs, off);
    float inv = rsqrtf(vs * (1.0f/128.0f) + 1e-5f);
    const float* gp = g + (size_t)fl*gstride;
    const float* bp = bb + (size_t)fl*gstride;
    float o0 = da*inv*gp[lane]      + bp[lane];
    float o1 = dc*inv*gp[64 + lane] + bp[64 + lane];
    float* xo = xout + row*128;
    xo[lane]      = o0;
    xo[64 + lane] = o1;
    xoutb[row*128 + lane]      = f2b(o0);
    xoutb[row*128 + 64 + lane] = f2b(o1);
}

// ---------------------------------------------------------------------------
// Softmax-pool over S (unchanged).
// ---------------------------------------------------------------------------
__global__ __launch_bounds__(256) void pool_kernel(
    const float* __restrict__ xB, const float* __restrict__ poolW,
    float* __restrict__ U, int f0)
{
    int f = f0 + blockIdx.x, b = blockIdx.y;
    const float* xb = xB + ((size_t)f*BS_ + (size_t)b*S_)*128;
    const float* pw = poolW + f*128;
    __shared__ float sc[512];
    __shared__ float red[8];
    __shared__ float MS[2];
    __shared__ float pool2[256];
    int t = threadIdx.x, lane = t & 63, w = t >> 6;

    float p0 = pw[lane], p1 = pw[64 + lane];
    for (int s = w; s < 512; s += 4) {
        float a = xb[(size_t)s*128 + lane]*p0 + xb[(size_t)s*128 + 64 + lane]*p1;
#pragma unroll
        for (int off = 1; off < 64; off <<= 1) a += __shfl_xor(a, off);
        if (lane == 0) sc[s] = a;
    }
    __syncthreads();

    float m = -1e30f;
    for (int s = t; s < 512; s += 256) m = fmaxf(m, sc[s]);
#pragma unroll
    for (int off = 1; off < 64; off <<= 1) m = fmaxf(m, __shfl_xor(m, off));
    if (lane == 0) red[w] = m;
    __syncthreads();
    if (t == 0) MS[0] = fmaxf(fmaxf(red[0], red[1]), fmaxf(red[2], red[3]));
    __syncthreads();
    float M = MS[0];

    float ssum = 0.f;
    for (int s = t; s < 512; s += 256) { float e = expf(sc[s] - M); sc[s] = e; ssum += e; }
#pragma unroll
    for (int off = 1; off < 64; off <<= 1) ssum += __shfl_xor(ssum, off);
    if (lane == 0) red[4 + w] = ssum;
    __syncthreads();
    if (t == 0) MS[1] = red[4] + red[5] + red[6] + red[7];
    __syncthreads();
    float inv = 1.0f / MS[1];

    int d = t & 127, hh = t >> 7;
    float a = 0.f;
    for (int s = hh*256; s < hh*256 + 256; ++s) a += sc[s]*xb[(size_t)s*128 + d];
    pool2[t] = a;
    __syncthreads();
    if (t < 128) U[((size_t)b*128 + d)*F_ + f] = (pool2[t] + pool2[t + 128]) * inv;
}

// ---------------------------------------------------------------------------
// Unified attention per (f,b) (unchanged).
// ---------------------------------------------------------------------------
__global__ __launch_bounds__(256) void unified_kernel(
    const float* __restrict__ U,
    const float* __restrict__ uQW, const float* __restrict__ uQB,
    const float* __restrict__ uKW, const float* __restrict__ uKB,
    const float* __restrict__ uVW, const float* __restrict__ uVB,
    float* __restrict__ outp)
{
    int f = blockIdx.x, b = blockIdx.y;
    __shared__ float Ub[128*9];
    __shared__ float Wj[128*9];
    __shared__ float zj[128];
    __shared__ float vm[128];
    __shared__ float Mm[81];
    __shared__ float wvm[9], bvec[9];
    __shared__ float cc_[2];
    int t = threadIdx.x;
    for (int i = t; i < 1152; i += 256) Ub[i] = U[(size_t)b*1152 + i];
    const float* qw = uQW + (size_t)f*1152;
    const float* kw = uKW + (size_t)f*1152;
    const float* vw = uVW + (size_t)f*1152;
    const float* qb = uQB + (size_t)f*128;
    const float* kb = uKB + (size_t)f*128;
    const float* vb = uVB + (size_t)f*128;

    if (t < 81) {
        int t1 = t/9, s1 = t%9; float a = 0.f;
        for (int kk = 0; kk < 128; ++kk) a += qw[kk*9 + t1]*kw[kk*9 + s1];
        Mm[t] = a;
    } else if (t < 90) {
        int s1 = t - 81; float a = 0.f;
        for (int kk = 0; kk < 128; ++kk) a += kw[kk*9 + s1]*qb[kk];
        bvec[s1] = a;
    } else if (t < 99) {
        int t1 = t - 90; float a = 0.f;
        for (int kk = 0; kk < 128; ++kk) a += vw[kk*9 + t1];
        wvm[t1] = a * (1.0f/128.0f);
    } else if (t == 99) {
        float a = 0.f, c2 = 0.f;
        for (int kk = 0; kk < 128; ++kk) { a += qb[kk]*kb[kk]; c2 += vb[kk]; }
        cc_[0] = a; cc_[1] = c2 * (1.0f/128.0f);
    }
    __syncthreads();

    if (t < 128) {
        int j = t;
        for (int t1 = 0; t1 < 9; ++t1) {
            float a = 0.f;
            for (int s1 = 0; s1 < 9; ++s1) a += Mm[t1*9 + s1]*Ub[j*9 + s1];
            Wj[j*9 + t1] = a;
        }
        float z = cc_[0], v2 = cc_[1];
        for (int s1 = 0; s1 < 9; ++s1) { z += bvec[s1]*Ub[j*9 + s1]; v2 += wvm[s1]*Ub[j*9 + s1]; }
        zj[j] = z; vm[j] = v2;
    }
    __syncthreads();

    int i = t >> 1, half = t & 1;
    float ui[9];
#pragma unroll
    for (int s1 = 0; s1 < 9; ++s1) ui[s1] = Ub[i*9 + s1];

    float mx = -1e30f;
    for (int jj = 0; jj < 64; ++jj) {
        int j = half*64 + jj;
        float a = zj[j];
#pragma unroll
        for (int s1 = 0; s1 < 9; ++s1) a += ui[s1]*Wj[j*9 + s1];
        mx = fmaxf(mx, a * (1.0f/3.0f));
    }
    mx = fmaxf(mx, __shfl_xor(mx, 1));
    float sum = 0.f, o = 0.f;
    for (int jj = 0; jj < 64; ++jj) {
        int j = half*64 + jj;
        float a = zj[j];
#pragma unroll
        for (int s1 = 0; s1 < 9; ++s1) a += ui[s1]*Wj[j*9 + s1];
        float p = expf(a * (1.0f/3.0f) - mx);
        sum += p; o += p*vm[j];
    }
    sum += __shfl_xor(sum, 1);
    o   += __shfl_xor(o, 1);
    if (half == 0) {
        float base;
        if (f > 0) base = ui[f];
        else { base = 0.f; for (int s1 = 0; s1 < 9; ++s1) base += ui[s1]; base *= (1.0f/9.0f); }
        outp[((size_t)b*128 + i)*10 + f] = o/sum + base;
    }
}

// ---------------------------------------------------------------------------
// Merge attention (features 3..8), writes output column 9 (unchanged).
// ---------------------------------------------------------------------------
__global__ __launch_bounds__(256) void merge_kernel(
    const float* __restrict__ U,
    const float* __restrict__ mQW, const float* __restrict__ mQB,
    const float* __restrict__ mKW, const float* __restrict__ mKB,
    const float* __restrict__ mVW, const float* __restrict__ mVB,
    float* __restrict__ outp)
{
    int b = blockIdx.x;
    __shared__ float Us[128*6];
    __shared__ float Wj[128*6];
    __shared__ float zj[128];
    __shared__ float vm[128];
    __shared__ float Mm[36];
    __shared__ float wvm[6], bvec[6];
    __shared__ float cc_[2];
    int t = threadIdx.x;
    for (int i = t; i < 768; i += 256) {
        int j = i/6, tt = i - j*6;
        Us[i] = U[(size_t)b*1152 + j*9 + 3 + tt];
    }
    if (t < 36) {
        int t1 = t/6, s1 = t%6; float a = 0.f;
        for (int kk = 0; kk < 128; ++kk) a += mQW[kk*6 + t1]*mKW[kk*6 + s1];
        Mm[t] = a;
    } else if (t < 42) {
        int s1 = t - 36; float a = 0.f;
        for (int kk = 0; kk < 128; ++kk) a += mKW[kk*6 + s1]*mQB[kk];
        bvec[s1] = a;
    } else if (t < 48) {
        int t1 = t - 42; float a = 0.f;
        for (int kk = 0; kk < 128; ++kk) a += mVW[kk*6 + t1];
        wvm[t1] = a * (1.0f/128.0f);
    } else if (t == 48) {
        float a = 0.f, c2 = 0.f;
        for (int kk = 0; kk < 128; ++kk) { a += mQB[kk]*mKB[kk]; c2 += mVB[kk]; }
        cc_[0] = a; cc_[1] = c2 * (1.0f/128.0f);
    }
    __syncthreads();

    if (t < 128) {
        int j = t;
        for (int t1 = 0; t1 < 6; ++t1) {
            float a = 0.f;
            for (int s1 = 0; s1 < 6; ++s1) a += Mm[t1*6 + s1]*Us[j*6 + s1];
            Wj[j*6 + t1] = a;
        }
        float z = cc_[0], v2 = cc_[1];
        for (int s1 = 0; s1 < 6; ++s1) { z += bvec[s1]*Us[j*6 + s1]; v2 += wvm[s1]*Us[j*6 + s1]; }
        zj[j] = z; vm[j] = v2;
    }
    __syncthreads();

    int i = t >> 1, half = t & 1;
    float ui[6];
#pragma unroll
    for (int s1 = 0; s1 < 6; ++s1) ui[s1] = Us[i*6 + s1];

    float mx = -1e30f;
    for (int jj = 0; jj < 64; ++jj) {
        int j = half*64 + jj;
        float a = zj[j];
#pragma unroll
        for (int s1 = 0; s1 < 6; ++s1) a += ui[s1]*Wj[j*6 + s1];
        mx = fmaxf(mx, a * (1.0f/3.0f));
    }
    mx = fmaxf(mx, __shfl_xor(mx, 1));
    float sum = 0.f, o = 0.f;
    for (int jj = 0; jj < 64; ++jj) {
        int j = half*64 + jj;
        float a = zj[j];
#pragma unroll
        for (int s1 = 0; s1 < 6; ++s1) a += ui[s1]*Wj[j*6 + s1];
        float p = expf(a * (1.0f/3.0f) - mx);
        sum += p; o += p*vm[j];
    }
    sum += __shfl_xor(sum, 1);
    o   += __shfl_xor(o, 1);
    if (half == 0) {
        float base = 0.f;
        for (int s1 = 0; s1 < 6; ++s1) base += ui[s1];
        base *= (1.0f/6.0f);
        outp[((size_t)b*128 + i)*10 + 9] = o/sum + base;
    }
}

// ---------------------------------------------------------------------------
extern "C" void kernel_launch(void* const* d_in, const int* in_sizes, int n_in,
                              void* d_out, int out_size, void* d_ws, size_t ws_size,
                              hipStream_t stream)
{
    const float* Y     = (const float*)d_in[0];
    const float* Gin   = (const float*)d_in[1];
    const float* posW1 = (const float*)d_in[2];
    const float* posB1 = (const float*)d_in[3];
    const float* posW2 = (const float*)d_in[4];
    const float* posB2 = (const float*)d_in[5];
    const float* posW3 = (const float*)d_in[6];
    const float* posB3 = (const float*)d_in[7];
    const float* Wq    = (const float*)d_in[8];
    const float* bq    = (const float*)d_in[9];
    const float* Wk    = (const float*)d_in[10];
    const float* bk    = (const float*)d_in[11];
    const float* Wv    = (const float*)d_in[12];
    const float* bv    = (const float*)d_in[13];
    const float* Wo    = (const float*)d_in[14];
    const float* bo    = (const float*)d_in[15];
    const float* lnG   = (const float*)d_in[16];
    const float* lnB   = (const float*)d_in[17];
    const float* fnG   = (const float*)d_in[18];
    const float* fnB   = (const float*)d_in[19];
    const float* poolW = (const float*)d_in[20];
    const float* uQW   = (const float*)d_in[21];
    const float* uQB   = (const float*)d_in[22];
    const float* uKW   = (const float*)d_in[23];
    const float* uKB   = (const float*)d_in[24];
    const float* uVW   = (const float*)d_in[25];
    const float* uVB   = (const float*)d_in[26];
    const float* mQW   = (const float*)d_in[27];
    const float* mQB   = (const float*)d_in[28];
    const float* mKW   = (const float*)d_in[29];
    const float* mKB   = (const float*)d_in[30];
    const float* mVW   = (const float*)d_in[31];
    const float* mVB   = (const float*)d_in[32];

    const size_t xelems = (size_t)F_ * BS_ * 128;     // 4,718,592
    char* p = (char*)d_ws;
    float* xA   = (float*)p;               p += xelems*4;
    float* xB   = (float*)p;               p += xelems*4;
    float* Ubuf = (float*)p;               p += 16384*4;
    unsigned short* xAb = (unsigned short*)p; p += xelems*2;
    unsigned short* Wqb = (unsigned short*)p; p += WELEMS*2;
    unsigned short* Wkb = (unsigned short*)p; p += WELEMS*2;
    unsigned short* Wvb = (unsigned short*)p; p += WELEMS*2;
    unsigned short* Wob = (unsigned short*)p; p += WELEMS*2;
    size_t fixed_bytes = (size_t)(p - (char*)d_ws);

    size_t avail = (ws_size > fixed_bytes) ? (ws_size - fixed_bytes) : 0;
    size_t per_f = 8UL * PERBUF;            // q(2B)+k(2B)+wv(2B)+Vt(2B eff) per elem
    int FC = (int)(avail / per_f);
    if (FC < 1) FC = 1;
    if (FC > F_) FC = F_;

    unsigned short* qb  = (unsigned short*)p;
    unsigned short* kb  = qb + (size_t)FC*PERBUF;
    unsigned short* wvb = kb + (size_t)FC*PERBUF;
    unsigned int*   vtb = (unsigned int*)(wvb + (size_t)FC*PERBUF);

    // Weight conversion to bf16 (once per launch, ~19 MB, single kernel)
    {
        int n = (int)WELEMS, gx = (n/8 + 255)/256;
        cvt4_kernel<<<dim3(gx, 4), 256, 0, stream>>>(
            Wq, Wk, Wv, Wo, Wqb, Wkb, Wvb, Wob, n);
    }

    posnet_kernel<<<dim3(128, F_), 256, 0, stream>>>(
        Y, Gin, posW1, posB1, posW2, posB2, posW3, posB3, xA, xAb);

    for (int l = 0; l < 2; ++l) {
        for (int f0 = 0; f0 < F_; f0 += FC) {
            int fc = (F_ - f0) < FC ? (F_ - f0) : FC;
            qkv_mfma_kernel<<<dim3(32, 8, 3*fc), 256, 0, stream>>>(
                xAb, Wqb, Wkb, Wvb, bq, bk, bv, qb, kb, vtb, l, f0);
            attn_mfma_kernel<<<dim3(256*fc), 256, 0, stream>>>(qb, kb, vtb, wvb);
            outproj_mfma_kernel<<<dim3(32, 1, fc), 256, 0, stream>>>(
                wvb, Wob, bo, xA, xB, l, f0);
            ln_kernel<<<dim3(fc*1024), 256, 0, stream>>>(
                xB, xA, xAb, lnG + (size_t)(l*F_ + f0)*128, lnB + (size_t)(l*F_ + f0)*128, f0, 128);
        }
    }

    for (int f0 = 0; f0 < F_; f0 += FC) {
        int fc = (F_ - f0) < FC ? (F_ - f0) : FC;
        ln_kernel<<<dim3(fc*1024), 256, 0, stream>>>(xA, xB, xAb, fnG, fnB, f0, 0);
        pool_kernel<<<dim3(fc, 8), 256, 0, stream>>>(xB, poolW, Ubuf, f0);
    }

    unified_kernel<<<dim3(F_, B_), 256, 0, stream>>>(
        Ubuf, uQW, uQB, uKW, uKB, uVW, uVB, (float*)d_out);
    merge_kernel<<<dim3(B_), 256, 0, stream>>>(
        Ubuf, mQW, mQB, mKW, mKB, mVW, mVB, (float*)d_out);
}